// Round 1
// 139.216 us; speedup vs baseline: 1.2841x; 1.2841x over previous
//
#include <hip/hip_runtime.h>
#include <math.h>

// Shapes (fixed by the reference)
#define B_  16
#define R_  4096
#define C_  16
#define OC_ 32
#define IC_ 32
#define CO_ 512   // C_*OC_
#define NIDX (B_*CO_)       // 8192 output elements
#define NGRP 16             // fallback stage-A p-groups

typedef unsigned int uint;
typedef unsigned short ushort;

typedef __attribute__((ext_vector_type(8))) short bf16x8;   // 8 bf16 = 4 VGPR
typedef __attribute__((ext_vector_type(4))) float f32x4;    // MFMA acc

__device__ __forceinline__ ushort f2bf(float f) {           // RNE float->bf16
  uint u = __float_as_uint(f);
  return (ushort)((u + 0x7FFFu + ((u >> 16) & 1u)) >> 16);
}
__device__ __forceinline__ float bf2f(ushort h) {
  return __uint_as_float(((uint)h) << 16);
}

// ---------------------------------------------------------------------------
// Pass 0 (MFMA): read W once (fp32, convert in-reg), u_hat[b,co] per route via
// one mfma_f32_16x16x32_bf16 per 16-co block. x is converted bf16 inline
// (per-lane fp32 load + RNE convert; x is tiny and L2-resident), removing the
// separate x_to_bf kernel and buffer. Writes u_hat bf16 [r][co][b] and
// uniform-sum partials s_part [blk][co][b]. No LDS, no syncthreads.
// Frag maps (m89/m97-verified): A row=lane&15 (=b), k=(lane>>4)*8+j contiguous;
// B col=lane&15 (=co), k contiguous; C/D col=lane&15 (=co), row b=(lane>>4)*4+reg.
// ---------------------------------------------------------------------------
__global__ __launch_bounds__(256)
void pass0_mfma(const float* __restrict__ x, const float* __restrict__ W,
                ushort* __restrict__ uhat, float* __restrict__ s_part,
                float* __restrict__ b_buf, int chunk)
{
  const int wid  = threadIdx.x >> 6;      // 0..3
  const int lane = threadIdx.x & 63;
  const int col  = lane & 15;             // = b for A, = co-offset for B/C
  const int krow = lane >> 4;             // 0..3
  const int r0   = blockIdx.x * chunk;

  // zero routing logits for this block's routes (replaces memset dispatch)
  for (int i = threadIdx.x; i < chunk * C_; i += 256) b_buf[r0 * C_ + i] = 0.f;

  f32x4 sacc[8];
#pragma unroll
  for (int j = 0; j < 8; ++j) sacc[j] = (f32x4){0.f, 0.f, 0.f, 0.f};

  for (int rr = 0; rr < chunk; ++rr) {
    const int r = r0 + rr;
    // A-frag: x[b=col][r][krow*8 .. +8] fp32 -> bf16 in-reg (32B load)
    const float* xp = x + ((size_t)col * R_ + r) * IC_ + krow * 8;
    float4 x0 = *(const float4*)xp;
    float4 x1 = *(const float4*)(xp + 4);
    bf16x8 af;
    af[0] = (short)f2bf(x0.x); af[1] = (short)f2bf(x0.y);
    af[2] = (short)f2bf(x0.z); af[3] = (short)f2bf(x0.w);
    af[4] = (short)f2bf(x1.x); af[5] = (short)f2bf(x1.y);
    af[6] = (short)f2bf(x1.z); af[7] = (short)f2bf(x1.w);

#pragma unroll
    for (int j = 0; j < 8; ++j) {
      const int co = (wid * 8 + j) * 16 + col;
      const float* wp = W + ((size_t)r * CO_ + co) * IC_ + krow * 8;
      float4 w0 = *(const float4*)(wp);
      float4 w1 = *(const float4*)(wp + 4);
      bf16x8 bf;
      bf[0] = (short)f2bf(w0.x); bf[1] = (short)f2bf(w0.y);
      bf[2] = (short)f2bf(w0.z); bf[3] = (short)f2bf(w0.w);
      bf[4] = (short)f2bf(w1.x); bf[5] = (short)f2bf(w1.y);
      bf[6] = (short)f2bf(w1.z); bf[7] = (short)f2bf(w1.w);

      f32x4 d = __builtin_amdgcn_mfma_f32_16x16x32_bf16(
          af, bf, (f32x4){0.f, 0.f, 0.f, 0.f}, 0, 0, 0);
      sacc[j] += d;

      // u_hat[r][co][b]: lane writes b = krow*4 .. +4 (8B, wave covers 512B)
      union { ushort us[4]; uint2 q; } pk;
      pk.us[0] = f2bf(d[0]); pk.us[1] = f2bf(d[1]);
      pk.us[2] = f2bf(d[2]); pk.us[3] = f2bf(d[3]);
      *(uint2*)(uhat + ((size_t)r * CO_ + co) * B_ + krow * 4) = pk.q;
    }
  }

  // s_part layout [blk][co*B_ + b]: lane owns co, b = krow*4..+4 -> 16B store
  float* sp = s_part + (size_t)blockIdx.x * NIDX;
#pragma unroll
  for (int j = 0; j < 8; ++j) {
    const int co = (wid * 8 + j) * 16 + col;
    *(f32x4*)(sp + co * B_ + krow * 4) = sacc[j];
  }
}

// ---------------------------------------------------------------------------
// Light pass: fused agreement(it) + weighted-sum(it+1), streaming u_hat (bf16)
// v and s_part in [co][b] layout.
// ---------------------------------------------------------------------------
__global__ __launch_bounds__(512)
void light_pass(const ushort* __restrict__ uhat, const float* __restrict__ v,
                float* __restrict__ b_buf, float* __restrict__ s_part,
                float* __restrict__ z_part, int chunk)
{
  const int t = threadIdx.x;                 // co = t
  const int c = t >> 5, o = t & 31;
  const int r0 = blockIdx.x * chunk;

  float vr[B_], sacc[B_];
#pragma unroll
  for (int k = 0; k < 4; ++k) *(float4*)&vr[4 * k] = *(const float4*)(v + t * B_ + 4 * k);
#pragma unroll
  for (int b = 0; b < B_; ++b) sacc[b] = 0.f;
  float zacc = 0.f;

#pragma unroll 2
  for (int rr = 0; rr < chunk; ++rr) {
    const int r = r0 + rr;
    const uint4* up = (const uint4*)(uhat + ((size_t)r * CO_ + t) * B_);
    union { ushort us[16]; uint4 q[2]; } pk;
    pk.q[0] = up[0]; pk.q[1] = up[1];
    float u[B_]; float aa = 0.f;
#pragma unroll
    for (int b = 0; b < B_; ++b) { u[b] = bf2f(pk.us[b]); aa = fmaf(u[b], vr[b], aa); }
#pragma unroll
    for (int off = 16; off >= 1; off >>= 1) aa += __shfl_xor(aa, off, 32);
    float bn = b_buf[r * C_ + c] + aa * (1.f / 16.f);
    float w  = __expf(bn);
    zacc += w;
    if (o == 0) b_buf[r * C_ + c] = bn;
#pragma unroll
    for (int b = 0; b < B_; ++b) sacc[b] = fmaf(w, u[b], sacc[b]);
  }
  float* sp = s_part + (size_t)blockIdx.x * NIDX;
#pragma unroll
  for (int k = 0; k < 4; ++k) *(float4*)(sp + t * B_ + 4 * k) = *(float4*)&sacc[4 * k];
  if (o == 0) z_part[blockIdx.x * C_ + c] = zacc;
}

// ---------------------------------------------------------------------------
// Fused final reduce + normalize + squash (replaces stageA + squashB chain).
// Grid 256 blocks x 256 threads: block handles 32 consecutive pos, 8 p-slices.
// All 256 CUs active; coalesced 128B segments per slice. One c per block.
// ---------------------------------------------------------------------------
template<int FINAL, int UNIFORM>
__global__ __launch_bounds__(256)
void reduce_squash(const float* __restrict__ s_part, const float* __restrict__ z_part,
                   float* __restrict__ v_buf, float* __restrict__ out, int NB)
{
  __shared__ float red[8][32];
  __shared__ float zw[4];
  const int t   = threadIdx.x;
  const int sl  = t >> 5;                        // p-slice 0..7
  const int pos = blockIdx.x * 32 + (t & 31);

  const float* base = s_part + pos;
  float a0 = 0.f, a1 = 0.f, a2 = 0.f, a3 = 0.f;
  for (int p = sl; p < NB; p += 32) {            // NB multiple of 32
    a0 += base[(size_t)(p)      * NIDX];
    a1 += base[(size_t)(p + 8)  * NIDX];
    a2 += base[(size_t)(p + 16) * NIDX];
    a3 += base[(size_t)(p + 24) * NIDX];
  }
  red[sl][t & 31] = (a0 + a1) + (a2 + a3);

  if (!UNIFORM) {
    const int c = blockIdx.x >> 4;               // single c per 32-pos block
    float zp = 0.f;
    for (int p = t; p < NB; p += 256) zp += z_part[p * C_ + c];
#pragma unroll
    for (int off = 32; off >= 1; off >>= 1) zp += __shfl_down(zp, off, 64);
    if ((t & 63) == 0) zw[t >> 6] = zp;
  }
  __syncthreads();

  if (t < 32) {
    float acc = 0.f;
#pragma unroll
    for (int s8 = 0; s8 < 8; ++s8) acc += red[s8][t];
    float Z = UNIFORM ? (float)R_ : ((zw[0] + zw[1]) + (zw[2] + zw[3]));
    const int p2 = blockIdx.x * 32 + t;          // co*16 + b
    float s  = acc / Z;
    float sq = s * s;
    float vv = sq * s / ((1.f + sq) * sqrtf(sq));   // exact reference formula
    if (FINAL) out[(p2 & 15) * CO_ + (p2 >> 4)] = vv;
    else       v_buf[p2] = vv;
  }
}

// ---------------------------------------------------------------------------
// FALLBACK kernels (used only if ws too small). [co][b] partials, two-stage.
// ---------------------------------------------------------------------------
__global__ __launch_bounds__(256)
void reduce_stageA(const float* __restrict__ s_part, const float* __restrict__ z_part,
                   float* __restrict__ s_mid, float* __restrict__ z_mid, int ppg)
{
  const int idx = blockIdx.x * 256 + threadIdx.x;
  const int g   = blockIdx.y;
  const float* base = s_part + (size_t)g * ppg * NIDX + idx;
  float a0 = 0.f, a1 = 0.f, a2 = 0.f, a3 = 0.f;
  for (int p = 0; p < ppg; p += 4) {
    a0 += base[(size_t)(p + 0) * NIDX];
    a1 += base[(size_t)(p + 1) * NIDX];
    a2 += base[(size_t)(p + 2) * NIDX];
    a3 += base[(size_t)(p + 3) * NIDX];
  }
  s_mid[(size_t)g * NIDX + idx] = (a0 + a1) + (a2 + a3);

  if (blockIdx.x == 0 && threadIdx.x < C_) {
    float z0 = 0.f, z1 = 0.f, z2 = 0.f, z3 = 0.f;
    const float* zb = z_part + (size_t)g * ppg * C_ + threadIdx.x;
    for (int p = 0; p < ppg; p += 4) {
      z0 += zb[(p + 0) * C_];
      z1 += zb[(p + 1) * C_];
      z2 += zb[(p + 2) * C_];
      z3 += zb[(p + 3) * C_];
    }
    z_mid[g * C_ + threadIdx.x] = (z0 + z1) + (z2 + z3);
  }
}

template<int FINAL, int UNIFORM>
__global__ __launch_bounds__(256)
void reduce_squashB(const float* __restrict__ s_mid, const float* __restrict__ z_mid,
                    float* __restrict__ v_buf, float* __restrict__ out)
{
  const int pos = blockIdx.x * 256 + threadIdx.x;   // co*16 + b
  const int co = pos >> 4, b = pos & 15;
  float acc = 0.f;
#pragma unroll
  for (int g = 0; g < NGRP; ++g) acc += s_mid[(size_t)g * NIDX + pos];
  float Z;
  if (UNIFORM) {
    Z = (float)R_;
  } else {
    const int c = co >> 5;
    float zs = 0.f;
#pragma unroll
    for (int g = 0; g < NGRP; ++g) zs += z_mid[g * C_ + c];
    Z = zs;
  }
  float s  = acc / Z;
  float sq = s * s;
  float vv = sq * s / ((1.f + sq) * sqrtf(sq));
  if (FINAL) out[b * CO_ + co] = vv; else v_buf[pos] = vv;
}

template<int MODE>
__global__ __launch_bounds__(256)
void heavy_pass(const float* __restrict__ x, const float* __restrict__ W,
                const float* __restrict__ v, float* __restrict__ b_buf,
                float* __restrict__ s_part, float* __restrict__ z_part,
                int chunk)
{
  const int t  = threadIdx.x;
  const int co0 = t, co1 = t + 256;
  const int c0 = co0 >> 5, o0 = co0 & 31;
  const int c1 = co1 >> 5;
  const int r0 = blockIdx.x * chunk;

  float sacc0[B_], sacc1[B_];
#pragma unroll
  for (int b = 0; b < B_; ++b) { sacc0[b] = 0.f; sacc1[b] = 0.f; }
  float v0r[B_], v1r[B_];
  if (MODE == 1) {
#pragma unroll
    for (int b = 0; b < B_; ++b) { v0r[b] = v[co0*B_ + b]; v1r[b] = v[co1*B_ + b]; }
  }
  float zacc0 = 0.f, zacc1 = 0.f;

  for (int rr = 0; rr < chunk; ++rr) {
    const int r = r0 + rr;
    const float* Wr = W + (size_t)r * (CO_*IC_);
    const float* xr = x + (size_t)r * IC_;
    float u0[B_], u1[B_];
#pragma unroll
    for (int b = 0; b < B_; ++b) { u0[b] = 0.f; u1[b] = 0.f; }
#pragma unroll
    for (int ic = 0; ic < IC_; ic += 8) {
      float w0c[8], w1c[8];
#pragma unroll
      for (int i = 0; i < 8; i += 4) {
        *(float4*)&w0c[i] = *(const float4*)&Wr[co0*IC_ + ic + i];
        *(float4*)&w1c[i] = *(const float4*)&Wr[co1*IC_ + ic + i];
      }
#pragma unroll
      for (int b = 0; b < B_; ++b) {
        const float* xb = xr + (size_t)b * (R_*IC_) + ic;
#pragma unroll
        for (int i = 0; i < 8; ++i) {
          float xv = xb[i];
          u0[b] = fmaf(w0c[i], xv, u0[b]);
          u1[b] = fmaf(w1c[i], xv, u1[b]);
        }
      }
    }
    float wgt0 = 1.f, wgt1 = 1.f;
    if (MODE == 1) {
      float aa0 = 0.f, aa1 = 0.f;
#pragma unroll
      for (int b = 0; b < B_; ++b) { aa0 = fmaf(u0[b], v0r[b], aa0); aa1 = fmaf(u1[b], v1r[b], aa1); }
#pragma unroll
      for (int off = 16; off >= 1; off >>= 1) { aa0 += __shfl_xor(aa0, off, 32); aa1 += __shfl_xor(aa1, off, 32); }
      float bn0 = b_buf[r*C_ + c0] + aa0 * (1.f/16.f);
      float bn1 = b_buf[r*C_ + c1] + aa1 * (1.f/16.f);
      wgt0 = __expf(bn0); wgt1 = __expf(bn1);
      zacc0 += wgt0; zacc1 += wgt1;
      if (o0 == 0) { b_buf[r*C_ + c0] = bn0; b_buf[r*C_ + c1] = bn1; }
    }
#pragma unroll
    for (int b = 0; b < B_; ++b) { sacc0[b] = fmaf(wgt0, u0[b], sacc0[b]); sacc1[b] = fmaf(wgt1, u1[b], sacc1[b]); }
  }
  float* sp = s_part + (size_t)blockIdx.x * NIDX;
#pragma unroll
  for (int b = 0; b < B_; ++b) { sp[co0*B_ + b] = sacc0[b]; sp[co1*B_ + b] = sacc1[b]; }
  if (MODE == 1 && o0 == 0) { z_part[blockIdx.x*C_ + c0] = zacc0; z_part[blockIdx.x*C_ + c1] = zacc1; }
}

extern "C" void kernel_launch(void* const* d_in, const int* in_sizes, int n_in,
                              void* d_out, int out_size, void* d_ws, size_t ws_size,
                              hipStream_t stream)
{
  const float* x = (const float*)d_in[0];   // [B, R, IC] fp32
  const float* W = (const float*)d_in[1];   // [R, C, OC, IC] fp32 (268 MB)
  float* out = (float*)d_out;               // [B, C, OC, 1] fp32 = 8192 floats

  const size_t uhat_elems = (size_t)R_ * CO_ * B_;       // 33.5M bf16 = 67 MB
  const int nidx_blks = NIDX / 256;                       // 32 (fallback)
  const int NBL_MAX = 512;                                // light-pass blocks

  // Fast path layout:
  // uhat(bf16) | s_part[NB0][8192] | z_part[NBL][16] | b_buf | v_buf
  int NB0 = 1024; bool fast = false;
  for (; NB0 >= 64; NB0 >>= 1) {
    size_t need = uhat_elems * 2 +
                  ((size_t)NB0 * NIDX + (size_t)NBL_MAX * C_ + (size_t)R_ * C_ + NIDX) * sizeof(float);
    if (need <= ws_size) { fast = true; break; }
  }

  if (fast) {
    const int NBL    = (NB0 < NBL_MAX) ? NB0 : NBL_MAX;
    const int chunk0 = R_ / NB0;             // 4 at NB0=1024
    const int chunkL = R_ / NBL;             // 8 at NBL=512
    ushort* uhat  = (ushort*)d_ws;
    float* s_part = (float*)(uhat + uhat_elems);
    float* z_part = s_part + (size_t)NB0 * NIDX;
    float* b_buf  = z_part + (size_t)NBL_MAX * C_;
    float* v_buf  = b_buf  + (size_t)R_ * C_;

    pass0_mfma<<<NB0, 256, 0, stream>>>(x, W, uhat, s_part, b_buf, chunk0);
    reduce_squash<0,1><<<NIDX/32, 256, 0, stream>>>(s_part, z_part, v_buf, nullptr, NB0);

    light_pass<<<NBL, 512, 0, stream>>>(uhat, v_buf, b_buf, s_part, z_part, chunkL);
    reduce_squash<0,0><<<NIDX/32, 256, 0, stream>>>(s_part, z_part, v_buf, nullptr, NBL);

    light_pass<<<NBL, 512, 0, stream>>>(uhat, v_buf, b_buf, s_part, z_part, chunkL);
    reduce_squash<1,0><<<NIDX/32, 256, 0, stream>>>(s_part, z_part, nullptr, out, NBL);
    return;
  }

  // Fallback: 3x W reads, two-stage reduce ([co][b] layouts)
  int NB = 512;
  while (NB > 64) {
    size_t need = ((size_t)NB * NIDX + (size_t)NB * C_ + (size_t)R_ * C_ + NIDX +
                   (size_t)NGRP * NIDX + NGRP * C_) * sizeof(float);
    if (need <= ws_size) break;
    NB >>= 1;
  }
  const int chunk = R_ / NB;
  const int ppg   = NB / NGRP;
  float* s_part = (float*)d_ws;
  float* z_part = s_part + (size_t)NB * NIDX;
  float* b_buf  = z_part + (size_t)NB * C_;
  float* v_buf  = b_buf  + (size_t)R_ * C_;
  float* s_mid  = v_buf  + NIDX;
  float* z_mid  = s_mid  + (size_t)NGRP * NIDX;

  (void)hipMemsetAsync(b_buf, 0, (size_t)R_ * C_ * sizeof(float), stream);
  heavy_pass<0><<<NB, 256, 0, stream>>>(x, W, nullptr, b_buf, s_part, z_part, chunk);
  reduce_stageA<<<dim3(nidx_blks, NGRP), 256, 0, stream>>>(s_part, z_part, s_mid, z_mid, ppg);
  reduce_squashB<0,1><<<nidx_blks, 256, 0, stream>>>(s_mid, z_mid, v_buf, nullptr);
  heavy_pass<1><<<NB, 256, 0, stream>>>(x, W, v_buf, b_buf, s_part, z_part, chunk);
  reduce_stageA<<<dim3(nidx_blks, NGRP), 256, 0, stream>>>(s_part, z_part, s_mid, z_mid, ppg);
  reduce_squashB<0,0><<<nidx_blks, 256, 0, stream>>>(s_mid, z_mid, v_buf, nullptr);
  heavy_pass<1><<<NB, 256, 0, stream>>>(x, W, v_buf, b_buf, s_part, z_part, chunk);
  reduce_stageA<<<dim3(nidx_blks, NGRP), 256, 0, stream>>>(s_part, z_part, s_mid, z_mid, ppg);
  reduce_squashB<1,0><<<nidx_blks, 256, 0, stream>>>(s_mid, z_mid, nullptr, out);
}

// Round 2
// 139.157 us; speedup vs baseline: 1.2847x; 1.0004x over previous
//
#include <hip/hip_runtime.h>
#include <hip/hip_cooperative_groups.h>
#include <math.h>

namespace cg = cooperative_groups;

// Shapes (fixed by the reference)
#define B_  16
#define R_  4096
#define C_  16
#define OC_ 32
#define IC_ 32
#define CO_ 512   // C_*OC_
#define NIDX (B_*CO_)       // 8192 output elements
#define NGRP 16             // fallback stage-A p-groups

// Cooperative path geometry
#define NBC   512           // blocks (2/CU on 256 CUs)
#define CHUNK 8             // routes per block = R_/NBC

typedef unsigned int uint;
typedef unsigned short ushort;

typedef __attribute__((ext_vector_type(8))) short bf16x8;   // 8 bf16 = 4 VGPR
typedef __attribute__((ext_vector_type(4))) float f32x4;    // MFMA acc

__device__ __forceinline__ ushort f2bf(float f) {           // RNE float->bf16
  uint u = __float_as_uint(f);
  return (ushort)((u + 0x7FFFu + ((u >> 16) & 1u)) >> 16);
}
__device__ __forceinline__ float bf2f(ushort h) {
  return __uint_as_float(((uint)h) << 16);
}

// ---------------------------------------------------------------------------
// Cooperative single-kernel path.
// 512 blocks x 256 threads, 2 blocks/CU. Each block owns 8 routes (r).
// u_hat for the block's routes lives ENTIRELY in VGPRs: per thread
// ureg[8 rr][8 j] = uint2 (4 bf16 = b krow*4..+4 of co (wid*8+j)*16+col).
// W is read exactly once from HBM; light phases are register-local; only the
// 16.8 MB s_part partials round-trip between grid syncs.
// Frag maps (m89/m97-verified): A row=lane&15 (=b), k=(lane>>4)*8+j contiguous;
// B col=lane&15 (=co), k contiguous; C/D col=lane&15 (=co), row b=(lane>>4)*4+reg.
// ---------------------------------------------------------------------------
__global__ __launch_bounds__(256, 2)
void coop_caps(const float* __restrict__ x, const float* __restrict__ W,
               float* __restrict__ s_part, float* __restrict__ z_part,
               float* __restrict__ v_buf, float* __restrict__ out)
{
  cg::grid_group grid = cg::this_grid();
  const int tid  = threadIdx.x;
  const int wid  = tid >> 6;
  const int lane = tid & 63;
  const int col  = lane & 15;
  const int krow = lane >> 4;
  const int blk  = blockIdx.x;
  const int r0   = blk * CHUNK;

  __shared__ float b_lds[4][CHUNK][4];   // [wave][rr][cidx]; c = wid*4+cidx
  __shared__ float red[16][17];
  __shared__ float zs_sh;

  // ---- preload x A-frags for all rr (fp32 -> bf16 in-reg; x is L2-hot) ----
  bf16x8 af[CHUNK];
#pragma unroll
  for (int rr = 0; rr < CHUNK; ++rr) {
    const float* xp = x + ((size_t)col * R_ + (r0 + rr)) * IC_ + krow * 8;
    float4 x0 = *(const float4*)xp;
    float4 x1 = *(const float4*)(xp + 4);
    af[rr][0] = (short)f2bf(x0.x); af[rr][1] = (short)f2bf(x0.y);
    af[rr][2] = (short)f2bf(x0.z); af[rr][3] = (short)f2bf(x0.w);
    af[rr][4] = (short)f2bf(x1.x); af[rr][5] = (short)f2bf(x1.y);
    af[rr][6] = (short)f2bf(x1.z); af[rr][7] = (short)f2bf(x1.w);
  }

  // init routing logits (block-owned; wave-local region, no barrier needed)
  if (lane < CHUNK * 4) b_lds[wid][lane >> 2][lane & 3] = 0.f;

  // ---- Phase 0: stream W once, u_hat -> registers, uniform-sum partials ----
  uint2 ureg[CHUNK][8];
  f32x4 sacc[8];
#pragma unroll
  for (int j = 0; j < 8; ++j) sacc[j] = (f32x4){0.f, 0.f, 0.f, 0.f};

#pragma unroll
  for (int rr = 0; rr < CHUNK; ++rr) {
    const int r = r0 + rr;
#pragma unroll
    for (int j = 0; j < 8; ++j) {
      const int co = (wid * 8 + j) * 16 + col;
      const float* wp = W + ((size_t)r * CO_ + co) * IC_ + krow * 8;
      float4 w0 = *(const float4*)(wp);
      float4 w1 = *(const float4*)(wp + 4);
      bf16x8 bf;
      bf[0] = (short)f2bf(w0.x); bf[1] = (short)f2bf(w0.y);
      bf[2] = (short)f2bf(w0.z); bf[3] = (short)f2bf(w0.w);
      bf[4] = (short)f2bf(w1.x); bf[5] = (short)f2bf(w1.y);
      bf[6] = (short)f2bf(w1.z); bf[7] = (short)f2bf(w1.w);

      f32x4 d = __builtin_amdgcn_mfma_f32_16x16x32_bf16(
          af[rr], bf, (f32x4){0.f, 0.f, 0.f, 0.f}, 0, 0, 0);
      sacc[j] += d;

      union { ushort us[4]; uint2 q; } pk;
      pk.us[0] = f2bf(d[0]); pk.us[1] = f2bf(d[1]);
      pk.us[2] = f2bf(d[2]); pk.us[3] = f2bf(d[3]);
      ureg[rr][j] = pk.q;      // statically indexed after unroll -> VGPRs
    }
  }
  {
    float* sp = s_part + (size_t)blk * NIDX;
#pragma unroll
    for (int j = 0; j < 8; ++j) {
      const int co = (wid * 8 + j) * 16 + col;
      *(f32x4*)(sp + co * B_ + krow * 4) = sacc[j];
    }
  }

  // ---- Reduce + squash phase (block owns co = blk, all 16 b) ----
  auto reduce_phase = [&](int round) {
    {
      const int b = tid & 15, sl = tid >> 4;        // 16 p-slices
      float a0 = 0.f, a1 = 0.f, a2 = 0.f, a3 = 0.f;
      const float* basep = s_part + blk * 16 + b;
#pragma unroll
      for (int p = sl; p < NBC; p += 64) {
        a0 += basep[(size_t)(p)      * NIDX];
        a1 += basep[(size_t)(p + 16) * NIDX];
        a2 += basep[(size_t)(p + 32) * NIDX];
        a3 += basep[(size_t)(p + 48) * NIDX];
      }
      red[sl][b] = (a0 + a1) + (a2 + a3);
    }
    if (round > 0 && tid < 64) {                    // softmax denominator Z[c]
      const int c = blk >> 5;
      float zp = 0.f;
#pragma unroll
      for (int k = 0; k < NBC / 64; ++k) zp += z_part[(tid + 64 * k) * C_ + c];
#pragma unroll
      for (int off = 32; off >= 1; off >>= 1) zp += __shfl_xor(zp, off, 64);
      if (tid == 0) zs_sh = zp;
    }
    __syncthreads();
    if (tid < 16) {
      float acc = 0.f;
#pragma unroll
      for (int s8 = 0; s8 < 16; ++s8) acc += red[s8][tid];
      float Z  = (round == 0) ? (float)R_ : zs_sh;
      float s  = acc / Z;
      float sq = s * s;
      float vv = sq * s / ((1.f + sq) * sqrtf(sq));   // exact reference formula
      if (round == 2) out[tid * CO_ + blk] = vv;      // transpose to [b][co]
      else            v_buf[blk * 16 + tid] = vv;     // [co][b]
    }
  };

  // ---- Light phase: agreement + b-update + weighted sum, all in registers ----
  auto light_phase = [&]() {
    float4 vr[8];
#pragma unroll
    for (int j = 0; j < 8; ++j) {
      const int co = (wid * 8 + j) * 16 + col;
      vr[j] = *(const float4*)(v_buf + co * B_ + krow * 4);
    }
#pragma unroll
    for (int j = 0; j < 8; ++j) sacc[j] = (f32x4){0.f, 0.f, 0.f, 0.f};
    float zacc[4] = {0.f, 0.f, 0.f, 0.f};

#pragma unroll
    for (int rr = 0; rr < CHUNK; ++rr) {
      float ap[4];
#pragma unroll
      for (int jj = 0; jj < 4; ++jj) {
        float s0 = 0.f;
#pragma unroll
        for (int jk = 0; jk < 2; ++jk) {
          const int j = jj * 2 + jk;
          uint2 q = ureg[rr][j];
          s0 = fmaf(__uint_as_float(q.x << 16),          vr[j].x, s0);
          s0 = fmaf(__uint_as_float(q.x & 0xFFFF0000u),  vr[j].y, s0);
          s0 = fmaf(__uint_as_float(q.y << 16),          vr[j].z, s0);
          s0 = fmaf(__uint_as_float(q.y & 0xFFFF0000u),  vr[j].w, s0);
        }
        ap[jj] = s0;
      }
      // full 64-lane butterfly: sums over all 16 b and the c's 32 o
#pragma unroll
      for (int off = 1; off <= 32; off <<= 1) {
#pragma unroll
        for (int jj = 0; jj < 4; ++jj) ap[jj] += __shfl_xor(ap[jj], off, 64);
      }
      float wexp[4];
#pragma unroll
      for (int jj = 0; jj < 4; ++jj) {
        float bn = b_lds[wid][rr][jj] + ap[jj] * (1.f / 16.f);
        wexp[jj] = __expf(bn);
        zacc[jj] += wexp[jj];
        if (lane == 0) b_lds[wid][rr][jj] = bn;
      }
#pragma unroll
      for (int j = 0; j < 8; ++j) {
        const float w = wexp[j >> 1];
        uint2 q = ureg[rr][j];
        sacc[j][0] = fmaf(w, __uint_as_float(q.x << 16),         sacc[j][0]);
        sacc[j][1] = fmaf(w, __uint_as_float(q.x & 0xFFFF0000u), sacc[j][1]);
        sacc[j][2] = fmaf(w, __uint_as_float(q.y << 16),         sacc[j][2]);
        sacc[j][3] = fmaf(w, __uint_as_float(q.y & 0xFFFF0000u), sacc[j][3]);
      }
    }
    float* sp = s_part + (size_t)blk * NIDX;
#pragma unroll
    for (int j = 0; j < 8; ++j) {
      const int co = (wid * 8 + j) * 16 + col;
      *(f32x4*)(sp + co * B_ + krow * 4) = sacc[j];
    }
    if (lane == 0) {
#pragma unroll
      for (int jj = 0; jj < 4; ++jj) z_part[blk * C_ + wid * 4 + jj] = zacc[jj];
    }
  };

  __threadfence(); grid.sync();
  reduce_phase(0);                 // v0 from uniform routing
  __threadfence(); grid.sync();
  light_phase();                   // iter 0 -> 1
  __threadfence(); grid.sync();
  reduce_phase(1);
  __threadfence(); grid.sync();
  light_phase();                   // iter 1 -> 2
  __threadfence(); grid.sync();
  reduce_phase(2);                 // final v -> out
}

// ---------------------------------------------------------------------------
// FALLBACK path A (R1 6-dispatch pipeline) — used if cooperative launch is
// unavailable. Identical to the previous round's verified kernels.
// ---------------------------------------------------------------------------
__global__ __launch_bounds__(256)
void pass0_mfma(const float* __restrict__ x, const float* __restrict__ W,
                ushort* __restrict__ uhat, float* __restrict__ s_part,
                float* __restrict__ b_buf, int chunk)
{
  const int wid  = threadIdx.x >> 6;
  const int lane = threadIdx.x & 63;
  const int col  = lane & 15;
  const int krow = lane >> 4;
  const int r0   = blockIdx.x * chunk;

  for (int i = threadIdx.x; i < chunk * C_; i += 256) b_buf[r0 * C_ + i] = 0.f;

  f32x4 sacc[8];
#pragma unroll
  for (int j = 0; j < 8; ++j) sacc[j] = (f32x4){0.f, 0.f, 0.f, 0.f};

  for (int rr = 0; rr < chunk; ++rr) {
    const int r = r0 + rr;
    const float* xp = x + ((size_t)col * R_ + r) * IC_ + krow * 8;
    float4 x0 = *(const float4*)xp;
    float4 x1 = *(const float4*)(xp + 4);
    bf16x8 af;
    af[0] = (short)f2bf(x0.x); af[1] = (short)f2bf(x0.y);
    af[2] = (short)f2bf(x0.z); af[3] = (short)f2bf(x0.w);
    af[4] = (short)f2bf(x1.x); af[5] = (short)f2bf(x1.y);
    af[6] = (short)f2bf(x1.z); af[7] = (short)f2bf(x1.w);

#pragma unroll
    for (int j = 0; j < 8; ++j) {
      const int co = (wid * 8 + j) * 16 + col;
      const float* wp = W + ((size_t)r * CO_ + co) * IC_ + krow * 8;
      float4 w0 = *(const float4*)(wp);
      float4 w1 = *(const float4*)(wp + 4);
      bf16x8 bf;
      bf[0] = (short)f2bf(w0.x); bf[1] = (short)f2bf(w0.y);
      bf[2] = (short)f2bf(w0.z); bf[3] = (short)f2bf(w0.w);
      bf[4] = (short)f2bf(w1.x); bf[5] = (short)f2bf(w1.y);
      bf[6] = (short)f2bf(w1.z); bf[7] = (short)f2bf(w1.w);

      f32x4 d = __builtin_amdgcn_mfma_f32_16x16x32_bf16(
          af, bf, (f32x4){0.f, 0.f, 0.f, 0.f}, 0, 0, 0);
      sacc[j] += d;

      union { ushort us[4]; uint2 q; } pk;
      pk.us[0] = f2bf(d[0]); pk.us[1] = f2bf(d[1]);
      pk.us[2] = f2bf(d[2]); pk.us[3] = f2bf(d[3]);
      *(uint2*)(uhat + ((size_t)r * CO_ + co) * B_ + krow * 4) = pk.q;
    }
  }

  float* sp = s_part + (size_t)blockIdx.x * NIDX;
#pragma unroll
  for (int j = 0; j < 8; ++j) {
    const int co = (wid * 8 + j) * 16 + col;
    *(f32x4*)(sp + co * B_ + krow * 4) = sacc[j];
  }
}

__global__ __launch_bounds__(512)
void light_pass(const ushort* __restrict__ uhat, const float* __restrict__ v,
                float* __restrict__ b_buf, float* __restrict__ s_part,
                float* __restrict__ z_part, int chunk)
{
  const int t = threadIdx.x;
  const int c = t >> 5, o = t & 31;
  const int r0 = blockIdx.x * chunk;

  float vr[B_], sacc[B_];
#pragma unroll
  for (int k = 0; k < 4; ++k) *(float4*)&vr[4 * k] = *(const float4*)(v + t * B_ + 4 * k);
#pragma unroll
  for (int b = 0; b < B_; ++b) sacc[b] = 0.f;
  float zacc = 0.f;

#pragma unroll 2
  for (int rr = 0; rr < chunk; ++rr) {
    const int r = r0 + rr;
    const uint4* up = (const uint4*)(uhat + ((size_t)r * CO_ + t) * B_);
    union { ushort us[16]; uint4 q[2]; } pk;
    pk.q[0] = up[0]; pk.q[1] = up[1];
    float u[B_]; float aa = 0.f;
#pragma unroll
    for (int b = 0; b < B_; ++b) { u[b] = bf2f(pk.us[b]); aa = fmaf(u[b], vr[b], aa); }
#pragma unroll
    for (int off = 16; off >= 1; off >>= 1) aa += __shfl_xor(aa, off, 32);
    float bn = b_buf[r * C_ + c] + aa * (1.f / 16.f);
    float w  = __expf(bn);
    zacc += w;
    if (o == 0) b_buf[r * C_ + c] = bn;
#pragma unroll
    for (int b = 0; b < B_; ++b) sacc[b] = fmaf(w, u[b], sacc[b]);
  }
  float* sp = s_part + (size_t)blockIdx.x * NIDX;
#pragma unroll
  for (int k = 0; k < 4; ++k) *(float4*)(sp + t * B_ + 4 * k) = *(float4*)&sacc[4 * k];
  if (o == 0) z_part[blockIdx.x * C_ + c] = zacc;
}

template<int FINAL, int UNIFORM>
__global__ __launch_bounds__(256)
void reduce_squash(const float* __restrict__ s_part, const float* __restrict__ z_part,
                   float* __restrict__ v_buf, float* __restrict__ out, int NB)
{
  __shared__ float red[8][32];
  __shared__ float zw[4];
  const int t   = threadIdx.x;
  const int sl  = t >> 5;
  const int pos = blockIdx.x * 32 + (t & 31);

  const float* base = s_part + pos;
  float a0 = 0.f, a1 = 0.f, a2 = 0.f, a3 = 0.f;
  for (int p = sl; p < NB; p += 32) {
    a0 += base[(size_t)(p)      * NIDX];
    a1 += base[(size_t)(p + 8)  * NIDX];
    a2 += base[(size_t)(p + 16) * NIDX];
    a3 += base[(size_t)(p + 24) * NIDX];
  }
  red[sl][t & 31] = (a0 + a1) + (a2 + a3);

  if (!UNIFORM) {
    const int c = blockIdx.x >> 4;
    float zp = 0.f;
    for (int p = t; p < NB; p += 256) zp += z_part[p * C_ + c];
#pragma unroll
    for (int off = 32; off >= 1; off >>= 1) zp += __shfl_down(zp, off, 64);
    if ((t & 63) == 0) zw[t >> 6] = zp;
  }
  __syncthreads();

  if (t < 32) {
    float acc = 0.f;
#pragma unroll
    for (int s8 = 0; s8 < 8; ++s8) acc += red[s8][t];
    float Z = UNIFORM ? (float)R_ : ((zw[0] + zw[1]) + (zw[2] + zw[3]));
    const int p2 = blockIdx.x * 32 + t;
    float s  = acc / Z;
    float sq = s * s;
    float vv = sq * s / ((1.f + sq) * sqrtf(sq));
    if (FINAL) out[(p2 & 15) * CO_ + (p2 >> 4)] = vv;
    else       v_buf[p2] = vv;
  }
}

// ---------------------------------------------------------------------------
// FALLBACK path B (no-ws heavy path) — unchanged.
// ---------------------------------------------------------------------------
__global__ __launch_bounds__(256)
void reduce_stageA(const float* __restrict__ s_part, const float* __restrict__ z_part,
                   float* __restrict__ s_mid, float* __restrict__ z_mid, int ppg)
{
  const int idx = blockIdx.x * 256 + threadIdx.x;
  const int g   = blockIdx.y;
  const float* base = s_part + (size_t)g * ppg * NIDX + idx;
  float a0 = 0.f, a1 = 0.f, a2 = 0.f, a3 = 0.f;
  for (int p = 0; p < ppg; p += 4) {
    a0 += base[(size_t)(p + 0) * NIDX];
    a1 += base[(size_t)(p + 1) * NIDX];
    a2 += base[(size_t)(p + 2) * NIDX];
    a3 += base[(size_t)(p + 3) * NIDX];
  }
  s_mid[(size_t)g * NIDX + idx] = (a0 + a1) + (a2 + a3);

  if (blockIdx.x == 0 && threadIdx.x < C_) {
    float z0 = 0.f, z1 = 0.f, z2 = 0.f, z3 = 0.f;
    const float* zb = z_part + (size_t)g * ppg * C_ + threadIdx.x;
    for (int p = 0; p < ppg; p += 4) {
      z0 += zb[(p + 0) * C_];
      z1 += zb[(p + 1) * C_];
      z2 += zb[(p + 2) * C_];
      z3 += zb[(p + 3) * C_];
    }
    z_mid[g * C_ + threadIdx.x] = (z0 + z1) + (z2 + z3);
  }
}

template<int FINAL, int UNIFORM>
__global__ __launch_bounds__(256)
void reduce_squashB(const float* __restrict__ s_mid, const float* __restrict__ z_mid,
                    float* __restrict__ v_buf, float* __restrict__ out)
{
  const int pos = blockIdx.x * 256 + threadIdx.x;
  const int co = pos >> 4, b = pos & 15;
  float acc = 0.f;
#pragma unroll
  for (int g = 0; g < NGRP; ++g) acc += s_mid[(size_t)g * NIDX + pos];
  float Z;
  if (UNIFORM) {
    Z = (float)R_;
  } else {
    const int c = co >> 5;
    float zs = 0.f;
#pragma unroll
    for (int g = 0; g < NGRP; ++g) zs += z_mid[g * C_ + c];
    Z = zs;
  }
  float s  = acc / Z;
  float sq = s * s;
  float vv = sq * s / ((1.f + sq) * sqrtf(sq));
  if (FINAL) out[b * CO_ + co] = vv; else v_buf[pos] = vv;
}

template<int MODE>
__global__ __launch_bounds__(256)
void heavy_pass(const float* __restrict__ x, const float* __restrict__ W,
                const float* __restrict__ v, float* __restrict__ b_buf,
                float* __restrict__ s_part, float* __restrict__ z_part,
                int chunk)
{
  const int t  = threadIdx.x;
  const int co0 = t, co1 = t + 256;
  const int c0 = co0 >> 5, o0 = co0 & 31;
  const int c1 = co1 >> 5;
  const int r0 = blockIdx.x * chunk;

  float sacc0[B_], sacc1[B_];
#pragma unroll
  for (int b = 0; b < B_; ++b) { sacc0[b] = 0.f; sacc1[b] = 0.f; }
  float v0r[B_], v1r[B_];
  if (MODE == 1) {
#pragma unroll
    for (int b = 0; b < B_; ++b) { v0r[b] = v[co0*B_ + b]; v1r[b] = v[co1*B_ + b]; }
  }
  float zacc0 = 0.f, zacc1 = 0.f;

  for (int rr = 0; rr < chunk; ++rr) {
    const int r = r0 + rr;
    const float* Wr = W + (size_t)r * (CO_*IC_);
    const float* xr = x + (size_t)r * IC_;
    float u0[B_], u1[B_];
#pragma unroll
    for (int b = 0; b < B_; ++b) { u0[b] = 0.f; u1[b] = 0.f; }
#pragma unroll
    for (int ic = 0; ic < IC_; ic += 8) {
      float w0c[8], w1c[8];
#pragma unroll
      for (int i = 0; i < 8; i += 4) {
        *(float4*)&w0c[i] = *(const float4*)&Wr[co0*IC_ + ic + i];
        *(float4*)&w1c[i] = *(const float4*)&Wr[co1*IC_ + ic + i];
      }
#pragma unroll
      for (int b = 0; b < B_; ++b) {
        const float* xb = xr + (size_t)b * (R_*IC_) + ic;
#pragma unroll
        for (int i = 0; i < 8; ++i) {
          float xv = xb[i];
          u0[b] = fmaf(w0c[i], xv, u0[b]);
          u1[b] = fmaf(w1c[i], xv, u1[b]);
        }
      }
    }
    float wgt0 = 1.f, wgt1 = 1.f;
    if (MODE == 1) {
      float aa0 = 0.f, aa1 = 0.f;
#pragma unroll
      for (int b = 0; b < B_; ++b) { aa0 = fmaf(u0[b], v0r[b], aa0); aa1 = fmaf(u1[b], v1r[b], aa1); }
#pragma unroll
      for (int off = 16; off >= 1; off >>= 1) { aa0 += __shfl_xor(aa0, off, 32); aa1 += __shfl_xor(aa1, off, 32); }
      float bn0 = b_buf[r*C_ + c0] + aa0 * (1.f/16.f);
      float bn1 = b_buf[r*C_ + c1] + aa1 * (1.f/16.f);
      wgt0 = __expf(bn0); wgt1 = __expf(bn1);
      zacc0 += wgt0; zacc1 += wgt1;
      if (o0 == 0) { b_buf[r*C_ + c0] = bn0; b_buf[r*C_ + c1] = bn1; }
    }
#pragma unroll
    for (int b = 0; b < B_; ++b) { sacc0[b] = fmaf(wgt0, u0[b], sacc0[b]); sacc1[b] = fmaf(wgt1, u1[b], sacc1[b]); }
  }
  float* sp = s_part + (size_t)blockIdx.x * NIDX;
#pragma unroll
  for (int b = 0; b < B_; ++b) { sp[co0*B_ + b] = sacc0[b]; sp[co1*B_ + b] = sacc1[b]; }
  if (MODE == 1 && o0 == 0) { z_part[blockIdx.x*C_ + c0] = zacc0; z_part[blockIdx.x*C_ + c1] = zacc1; }
}

extern "C" void kernel_launch(void* const* d_in, const int* in_sizes, int n_in,
                              void* d_out, int out_size, void* d_ws, size_t ws_size,
                              hipStream_t stream)
{
  const float* x = (const float*)d_in[0];   // [B, R, IC] fp32
  const float* W = (const float*)d_in[1];   // [R, C, OC, IC] fp32 (268 MB)
  float* out = (float*)d_out;               // [B, C, OC, 1] fp32 = 8192 floats

  // ---------------- Cooperative single-kernel path ----------------
  {
    const size_t need_coop =
        ((size_t)NBC * NIDX + (size_t)NBC * C_ + NIDX) * sizeof(float);
    if (need_coop <= ws_size) {
      int dev = 0;
      (void)hipGetDevice(&dev);
      int coopOK = 0;
      (void)hipDeviceGetAttribute(&coopOK, hipDeviceAttributeCooperativeLaunch, dev);
      int numCU = 0;
      (void)hipDeviceGetAttribute(&numCU, hipDeviceAttributeMultiprocessorCount, dev);
      int maxBlk = 0;
      hipError_t oe = hipOccupancyMaxActiveBlocksPerMultiprocessor(
          &maxBlk, coop_caps, 256, 0);
      if (coopOK && oe == hipSuccess && (long)maxBlk * numCU >= NBC) {
        float* s_part = (float*)d_ws;
        float* z_part = s_part + (size_t)NBC * NIDX;
        float* v_buf  = z_part + (size_t)NBC * C_;
        void* args[] = {(void*)&x, (void*)&W, (void*)&s_part,
                        (void*)&z_part, (void*)&v_buf, (void*)&out};
        hipError_t le = hipLaunchCooperativeKernel(
            coop_caps, dim3(NBC), dim3(256), args, 0, stream);
        if (le == hipSuccess) return;
      }
    }
  }

  // ---------------- Fallback A: 6-dispatch pipeline (R1) ----------------
  const size_t uhat_elems = (size_t)R_ * CO_ * B_;       // 67 MB bf16
  const int nidx_blks = NIDX / 256;
  const int NBL_MAX = 512;

  int NB0 = 1024; bool fast = false;
  for (; NB0 >= 64; NB0 >>= 1) {
    size_t need = uhat_elems * 2 +
                  ((size_t)NB0 * NIDX + (size_t)NBL_MAX * C_ + (size_t)R_ * C_ + NIDX) * sizeof(float);
    if (need <= ws_size) { fast = true; break; }
  }

  if (fast) {
    const int NBL    = (NB0 < NBL_MAX) ? NB0 : NBL_MAX;
    const int chunk0 = R_ / NB0;
    const int chunkL = R_ / NBL;
    ushort* uhat  = (ushort*)d_ws;
    float* s_part = (float*)(uhat + uhat_elems);
    float* z_part = s_part + (size_t)NB0 * NIDX;
    float* b_buf  = z_part + (size_t)NBL_MAX * C_;
    float* v_buf  = b_buf  + (size_t)R_ * C_;

    pass0_mfma<<<NB0, 256, 0, stream>>>(x, W, uhat, s_part, b_buf, chunk0);
    reduce_squash<0,1><<<NIDX/32, 256, 0, stream>>>(s_part, z_part, v_buf, nullptr, NB0);

    light_pass<<<NBL, 512, 0, stream>>>(uhat, v_buf, b_buf, s_part, z_part, chunkL);
    reduce_squash<0,0><<<NIDX/32, 256, 0, stream>>>(s_part, z_part, v_buf, nullptr, NBL);

    light_pass<<<NBL, 512, 0, stream>>>(uhat, v_buf, b_buf, s_part, z_part, chunkL);
    reduce_squash<1,0><<<NIDX/32, 256, 0, stream>>>(s_part, z_part, nullptr, out, NBL);
    return;
  }

  // ---------------- Fallback B: heavy path ----------------
  int NB = 512;
  while (NB > 64) {
    size_t need = ((size_t)NB * NIDX + (size_t)NB * C_ + (size_t)R_ * C_ + NIDX +
                   (size_t)NGRP * NIDX + NGRP * C_) * sizeof(float);
    if (need <= ws_size) break;
    NB >>= 1;
  }
  const int chunk = R_ / NB;
  const int ppg   = NB / NGRP;
  float* s_part = (float*)d_ws;
  float* z_part = s_part + (size_t)NB * NIDX;
  float* b_buf  = z_part + (size_t)NB * C_;
  float* v_buf  = b_buf  + (size_t)R_ * C_;
  float* s_mid  = v_buf  + NIDX;
  float* z_mid  = s_mid  + (size_t)NGRP * NIDX;

  (void)hipMemsetAsync(b_buf, 0, (size_t)R_ * C_ * sizeof(float), stream);
  heavy_pass<0><<<NB, 256, 0, stream>>>(x, W, nullptr, b_buf, s_part, z_part, chunk);
  reduce_stageA<<<dim3(nidx_blks, NGRP), 256, 0, stream>>>(s_part, z_part, s_mid, z_mid, ppg);
  reduce_squashB<0,1><<<nidx_blks, 256, 0, stream>>>(s_mid, z_mid, v_buf, nullptr);
  heavy_pass<1><<<NB, 256, 0, stream>>>(x, W, v_buf, b_buf, s_part, z_part, chunk);
  reduce_stageA<<<dim3(nidx_blks, NGRP), 256, 0, stream>>>(s_part, z_part, s_mid, z_mid, ppg);
  reduce_squashB<0,0><<<nidx_blks, 256, 0, stream>>>(s_mid, z_mid, v_buf, nullptr);
  heavy_pass<1><<<NB, 256, 0, stream>>>(x, W, v_buf, b_buf, s_part, z_part, chunk);
  reduce_stageA<<<dim3(nidx_blks, NGRP), 256, 0, stream>>>(s_part, z_part, s_mid, z_mid, ppg);
  reduce_squashB<1,0><<<nidx_blks, 256, 0, stream>>>(s_mid, z_mid, nullptr, out);
}